// Round 6
// baseline (206.636 us; speedup 1.0000x reference)
//
#include <hip/hip_runtime.h>
#include <math.h>

#define B_   2
#define S_   2048
#define H_   1024
#define NH_  16
#define NKV_ 4
#define HD_  64
#define R_   (NH_ / NKV_)   // 4 q-heads per kv-head
#define QKVW 1536           // qkv row width (q 0..1023 | k 1024..1279 | v 1280..1535)

typedef __attribute__((ext_vector_type(8))) short bf16x8;
typedef __attribute__((ext_vector_type(4))) float f32x4;

__device__ inline short f2bf(float f) {
    unsigned u = __float_as_uint(f);
    u += 0x7FFF + ((u >> 16) & 1);     // RNE to bf16
    return (short)(u >> 16);
}

// async global->LDS, 16 B per lane; lptr is the wave-uniform chunk base,
// HW scatters lane i's 16 B at lptr + i*16 (m97/m104 semantics).
__device__ inline void gload_lds16(const void* gptr, void* lptr) {
    __builtin_amdgcn_global_load_lds(
        (const __attribute__((address_space(1))) unsigned int*)gptr,
        (__attribute__((address_space(3))) unsigned int*)lptr,
        16, 0, 0);
}

// ---------------------------------------------------------------------------
// Weight transposes + x->bf16 convert in one launch. 896 blocks:
// [0,640) = 64x64 transpose tiles (Wq/Wk/Wv/Wo as before);
// [640,896) = xb = bf16(x), 16384 elements per block (to d_out scratch).
// ---------------------------------------------------------------------------
__global__ __launch_bounds__(256) void tconv_all(const float* __restrict__ Wq,
                                                 const float* __restrict__ Wk,
                                                 const float* __restrict__ Wv,
                                                 const float* __restrict__ Wo,
                                                 short* __restrict__ Wqkvt,
                                                 short* __restrict__ Wot,
                                                 const float* __restrict__ x,
                                                 short* __restrict__ xb) {
    const int bx = blockIdx.x;
    const int tid = threadIdx.x;

    if (bx >= 640) {           // ---- x -> bf16 convert (block-uniform path) ----
        const size_t e0 = (size_t)(bx - 640) * 16384;
#pragma unroll
        for (int t = 0; t < 8; t++) {
            const size_t i = e0 + ((size_t)t * 256 + tid) * 8;
            float4 a = *(const float4*)&x[i];
            float4 c = *(const float4*)&x[i + 4];
            bf16x8 o;
            o[0] = f2bf(a.x); o[1] = f2bf(a.y); o[2] = f2bf(a.z); o[3] = f2bf(a.w);
            o[4] = f2bf(c.x); o[5] = f2bf(c.y); o[6] = f2bf(c.z); o[7] = f2bf(c.w);
            *(bf16x8*)&xb[i] = o;
        }
        return;
    }

    __shared__ short T[64][68];
    const float* W; short* Wt; int N, idx;
    if (bx < 256)      { W = Wq; Wt = Wqkvt;                     N = 1024; idx = bx; }
    else if (bx < 320) { W = Wk; Wt = Wqkvt + 1024 * 1024;       N = 256;  idx = bx - 256; }
    else if (bx < 384) { W = Wv; Wt = Wqkvt + 1280 * 1024;       N = 256;  idx = bx - 320; }
    else               { W = Wo; Wt = Wot;                       N = 1024; idx = bx - 384; }
    const int ntiles = N >> 6;
    const int n0 = (idx % ntiles) * 64;
    const int k0 = (idx / ntiles) * 64;

    const int r  = tid >> 4;
    const int c4 = (tid & 15) * 4;
#pragma unroll
    for (int t = 0; t < 4; t++) {
        int row = t * 16 + r;
        float4 v = *(const float4*)&W[(size_t)(k0 + row) * N + n0 + c4];
        T[c4 + 0][row] = f2bf(v.x);
        T[c4 + 1][row] = f2bf(v.y);
        T[c4 + 2][row] = f2bf(v.z);
        T[c4 + 3][row] = f2bf(v.w);
    }
    __syncthreads();
#pragma unroll
    for (int t = 0; t < 4; t++) {
        int row = t * 16 + r;          // n index
        short4 o = *(short4*)&T[row][c4];
        *(short4*)&Wt[(size_t)(n0 + row) * 1024 + k0 + c4] = o;
    }
}

// ---------------------------------------------------------------------------
// Fused GEMM1 v2: qkv = xb @ Wqkvt^T, m97-class 128x128 tile, BK=32,
// 256 threads = 4 waves (2x2, 64x64 acc[4][4] each), all staging via
// global_load_lds width-16. RoPE epilogue for q/k cols; v cols scattered
// transposed into Vtg. (xb precomputed bf16 of x, lives in d_out scratch.)
// ---------------------------------------------------------------------------
__global__ __launch_bounds__(256) void gemm1_fused(const short* __restrict__ xb,
                                                   const short* __restrict__ Bt,
                                                   short* __restrict__ qkv,
                                                   short* __restrict__ Vtg,
                                                   const float* __restrict__ cosb,
                                                   const float* __restrict__ sinb) {
    __shared__ short Ah[128 * 32];   // [row][k] 8 KB
    __shared__ short Bh[128 * 32];   // [col][k] 8 KB

    const int tid  = threadIdx.x;
    const int w    = tid >> 6;
    const int lane = tid & 63;
    const int ln   = lane & 15;
    const int qd   = lane >> 4;
    const int wr   = w >> 1, wc = w & 1;
    const int row0 = blockIdx.y * 128;
    const int col0 = blockIdx.x * 128;

    const int sr = lane >> 2;        // 0..15 staging row-in-chunk
    const int sk = (lane & 3) * 8;   // k element offset

    f32x4 acc[4][4];
#pragma unroll
    for (int mi = 0; mi < 4; mi++)
#pragma unroll
        for (int ni = 0; ni < 4; ni++)
            acc[mi][ni] = (f32x4){0.f, 0.f, 0.f, 0.f};

    for (int k0 = 0; k0 < 1024; k0 += 32) {
        __syncthreads();   // previous iter's frag reads done
        // wave w stages A rows w*16+[0,16) and 64+w*16+[0,16); same for B cols
        gload_lds16(xb + (size_t)(row0 + w * 16 + sr) * 1024 + k0 + sk,      &Ah[(w * 16) * 32]);
        gload_lds16(xb + (size_t)(row0 + 64 + w * 16 + sr) * 1024 + k0 + sk, &Ah[(64 + w * 16) * 32]);
        gload_lds16(Bt + (size_t)(col0 + w * 16 + sr) * 1024 + k0 + sk,      &Bh[(w * 16) * 32]);
        gload_lds16(Bt + (size_t)(col0 + 64 + w * 16 + sr) * 1024 + k0 + sk, &Bh[(64 + w * 16) * 32]);
        __syncthreads();

        bf16x8 af[4], bf[4];
#pragma unroll
        for (int mi = 0; mi < 4; mi++)
            af[mi] = *(const bf16x8*)&Ah[(wr * 64 + mi * 16 + ln) * 32 + qd * 8];
#pragma unroll
        for (int ni = 0; ni < 4; ni++)
            bf[ni] = *(const bf16x8*)&Bh[(wc * 64 + ni * 16 + ln) * 32 + qd * 8];
#pragma unroll
        for (int mi = 0; mi < 4; mi++)
#pragma unroll
            for (int ni = 0; ni < 4; ni++)
                acc[mi][ni] = __builtin_amdgcn_mfma_f32_16x16x32_bf16(af[mi], bf[ni], acc[mi][ni], 0, 0, 0);
    }

    const int colw = col0 + wc * 64;          // this wave's 64-col half
    if (colw < H_ + NKV_ * HD_) {
        // ---- q or k columns: RoPE in fp32, store bf16 to qkv ----
#pragma unroll
        for (int mi = 0; mi < 4; mi++)
#pragma unroll
            for (int i = 0; i < 4; i++) {
                const int row  = row0 + wr * 64 + mi * 16 + qd * 4 + i;
                const int spos = row & (S_ - 1);
                const float* cp = cosb + (size_t)spos * HD_;
                const float* sp = sinb + (size_t)spos * HD_;
                float o0[4];
#pragma unroll
                for (int ni = 0; ni < 2; ni++) {
                    const int d = ni * 16 + ln;
                    float x0 = acc[mi][ni][i], x1 = acc[mi][ni + 2][i];
                    o0[ni]     = x0 * cp[d]      - x1 * sp[d];
                    o0[ni + 2] = x1 * cp[d + 32] + x0 * sp[d + 32];
                }
                short* Cp = qkv + (size_t)row * QKVW + colw + ln;
#pragma unroll
                for (int ni = 0; ni < 4; ni++) Cp[ni * 16] = f2bf(o0[ni]);
            }
    } else {
        // ---- v columns: transposed scatter into Vtg[(b*NKV+g)*HD+d][s] ----
        const int g = (colw - (H_ + NKV_ * HD_)) >> 6;
#pragma unroll
        for (int mi = 0; mi < 4; mi++) {
            const int rbase = row0 + wr * 64 + mi * 16 + qd * 4;   // i = +0..3
            const int bg = ((rbase >> 11) * NKV_) + g;
            const int s0 = rbase & (S_ - 1);
#pragma unroll
            for (int ni = 0; ni < 4; ni++) {
                const int d = ni * 16 + ln;
                short4 pk = { f2bf(acc[mi][ni][0]), f2bf(acc[mi][ni][1]),
                              f2bf(acc[mi][ni][2]), f2bf(acc[mi][ni][3]) };
                *(short4*)&Vtg[((size_t)bg * HD_ + d) * S_ + s0] = pk;
            }
        }
    }
}

// ---------------------------------------------------------------------------
// bf16 MFMA GEMM v2, B^T form: C[M,N] = A[M,K] @ Bt[N,K]^T (fp32 out).
// m97-class 128x128 tile, BK=32, 256 threads (2x2 waves, acc[4][4]).
// ---------------------------------------------------------------------------
__global__ __launch_bounds__(256) void gemm2_bt(const short* __restrict__ A, int lda,
                                                const short* __restrict__ Bt,
                                                float* __restrict__ C, int ldc,
                                                int K) {
    __shared__ short Ah[128 * 32];
    __shared__ short Bh[128 * 32];

    const int tid  = threadIdx.x;
    const int w    = tid >> 6;
    const int lane = tid & 63;
    const int ln   = lane & 15;
    const int qd   = lane >> 4;
    const int wr   = w >> 1, wc = w & 1;
    const int row0 = blockIdx.y * 128;
    const int col0 = blockIdx.x * 128;

    const int sr = lane >> 2;
    const int sk = (lane & 3) * 8;

    f32x4 acc[4][4];
#pragma unroll
    for (int mi = 0; mi < 4; mi++)
#pragma unroll
        for (int ni = 0; ni < 4; ni++)
            acc[mi][ni] = (f32x4){0.f, 0.f, 0.f, 0.f};

    for (int k0 = 0; k0 < K; k0 += 32) {
        __syncthreads();
        gload_lds16(A + (size_t)(row0 + w * 16 + sr) * lda + k0 + sk,      &Ah[(w * 16) * 32]);
        gload_lds16(A + (size_t)(row0 + 64 + w * 16 + sr) * lda + k0 + sk, &Ah[(64 + w * 16) * 32]);
        gload_lds16(Bt + (size_t)(col0 + w * 16 + sr) * K + k0 + sk,       &Bh[(w * 16) * 32]);
        gload_lds16(Bt + (size_t)(col0 + 64 + w * 16 + sr) * K + k0 + sk,  &Bh[(64 + w * 16) * 32]);
        __syncthreads();

        bf16x8 af[4], bf[4];
#pragma unroll
        for (int mi = 0; mi < 4; mi++)
            af[mi] = *(const bf16x8*)&Ah[(wr * 64 + mi * 16 + ln) * 32 + qd * 8];
#pragma unroll
        for (int ni = 0; ni < 4; ni++)
            bf[ni] = *(const bf16x8*)&Bh[(wc * 64 + ni * 16 + ln) * 32 + qd * 8];
#pragma unroll
        for (int mi = 0; mi < 4; mi++)
#pragma unroll
            for (int ni = 0; ni < 4; ni++)
                acc[mi][ni] = __builtin_amdgcn_mfma_f32_16x16x32_bf16(af[mi], bf[ni], acc[mi][ni], 0, 0, 0);
    }

#pragma unroll
    for (int mi = 0; mi < 4; mi++)
#pragma unroll
        for (int i = 0; i < 4; i++) {
            const size_t row = row0 + wr * 64 + mi * 16 + qd * 4 + i;
            float* Cp = C + row * ldc + col0 + wc * 64 + ln;
#pragma unroll
            for (int ni = 0; ni < 4; ni++) Cp[ni * 16] = acc[mi][ni][i];
        }
}

// ---------------------------------------------------------------------------
// bf16 MFMA flash attention v15 (UNCHANGED from R5, measured 77.5 us):
// LDS-staged K/V shared by 8 waves, uniform pair-blocks, one barrier/tile.
// Post-mortem note: now ~softmax-VALU-issue-bound (~5500 cyc per sequential
// tile-step invariant across v12/v15); left alone this round.
// ---------------------------------------------------------------------------
__global__ __launch_bounds__(512, 2) void attn_kernel(short* __restrict__ qkv,
                                                      const short* __restrict__ Vtg,
                                                      const float* __restrict__ maskb) {
    const int tid  = threadIdx.x;
    const int w    = tid >> 6;           // 0..7
    const int lane = tid & 63;
    const int ln   = lane & 15;
    const int qd   = lane >> 4;

    // fid&7 = bg -> XCD affinity for the K/V slice
    const int fid = blockIdx.x;          // 0..255
    const int bg  = fid & 7;             // b*NKV+g
    const int u   = fid >> 3;            // 0..31
    const int b   = bg >> 2;
    const int g   = bg & 3;
    const int h   = g * R_ + (u & 3);
    const int a   = u >> 2;              // pair index 0..7

    const int qt   = (w < 4) ? a : (15 - a);
    const int st   = w & 3;              // strip within q-tile
    const int rowb = qt * 128 + st * 32; // wave's first q-row
    const int ktd  = 2 * qt + (st >> 1); // wave's diagonal (last) tile
    const int nt   = 32 - 2 * a;         // tiles staged by this block

    __shared__ short Ks[2][64 * 72];     // K  [key][dim], stride 72
    __shared__ short Vt[2][64 * 72];     // V^T [dim][key]
    __shared__ short Ps[8][16 * 72];     // per-wave P round-trip (one rg)
    __shared__ float mskS[2][64];
    short* const ps = Ps[w];

    const short* const Kb = qkv + (size_t)b * S_ * QKVW + H_ + g * HD_;
    const short* const Vb = Vtg + (size_t)bg * HD_ * S_;
    const float* const mb = maskb + b * S_;

    const int fr = tid >> 3;             // 0..63 (staging row)
    const int fc = (tid & 7) * 8;        // staging col (elements)

    // ---- Q B-frags: rows rowb+rg*16+ln ----
    bf16x8 qf[2][2];
#pragma unroll
    for (int rg = 0; rg < 2; rg++) {
        const short* qp = qkv + (size_t)(b * S_ + rowb + rg * 16 + ln) * QKVW + h * HD_;
        qf[rg][0] = *(const bf16x8*)&qp[qd * 8];
        qf[rg][1] = *(const bf16x8*)&qp[32 + qd * 8];
    }

    f32x4 O[2][4] = {};
    float mrow[2] = {-1e30f, -1e30f};
    float lrow[2] = {0.0f, 0.0f};

    // ---- stage tile 0 (coalesced: 8 threads x 16 B per row) ----
    *(bf16x8*)&Ks[0][fr * 72 + fc] = *(const bf16x8*)&Kb[(size_t)fr * QKVW + fc];
    *(bf16x8*)&Vt[0][fr * 72 + fc] = *(const bf16x8*)&Vb[(size_t)fr * S_ + fc];
    if (tid < 64) mskS[0][tid] = mb[tid];
    __syncthreads();

    int cur = 0;
    for (int kt = 0; kt < nt; kt++) {
        const int base = kt * 64;
        const bool pf = (kt + 1 < nt);

        // ---- prefetch tile kt+1 into registers (no wait) ----
        bf16x8 pk, pv;
        float pm = 0.0f;
        if (pf) {
            const int nb = base + 64;
            pk = *(const bf16x8*)&Kb[(size_t)(nb + fr) * QKVW + fc];
            pv = *(const bf16x8*)&Vb[(size_t)fr * S_ + nb + fc];
            if (tid < 64) pm = mb[nb + tid];
        }

        if (kt <= ktd) {   // wave-uniform: tile has unmasked keys for this wave
            // ---- QK^T swapped: St[rg][kg] = S^T tile ----
            f32x4 St[2][4];
#pragma unroll
            for (int kg = 0; kg < 4; kg++) {
                bf16x8 ka0 = *(const bf16x8*)&Ks[cur][(kg * 16 + ln) * 72 + qd * 8];
                bf16x8 ka1 = *(const bf16x8*)&Ks[cur][(kg * 16 + ln) * 72 + 32 + qd * 8];
#pragma unroll
                for (int rg = 0; rg < 2; rg++) {
                    f32x4 z = {0.f, 0.f, 0.f, 0.f};
                    z = __builtin_amdgcn_mfma_f32_16x16x32_bf16(ka0, qf[rg][0], z, 0, 0, 0);
                    St[rg][kg] = __builtin_amdgcn_mfma_f32_16x16x32_bf16(ka1, qf[rg][1], z, 0, 0, 0);
                }
            }

            // ---- V B-frags from LDS (shared across rgs) ----
            bf16x8 vb[2][4];
#pragma unroll
            for (int kc2 = 0; kc2 < 2; kc2++)
#pragma unroll
                for (int dt = 0; dt < 4; dt++)
                    vb[kc2][dt] = *(const bf16x8*)&Vt[cur][(dt * 16 + ln) * 72 + kc2 * 32 + qd * 8];

            // ---- per-lane mask bias for keys base+kg*16+qd*4+i ----
            float mt[4][4];
#pragma unroll
            for (int kg = 0; kg < 4; kg++) {
                float4 mv = *(const float4*)&mskS[cur][kg * 16 + qd * 4];
                mt[kg][0] = (1.0f - mv.x) * -1e9f;
                mt[kg][1] = (1.0f - mv.y) * -1e9f;
                mt[kg][2] = (1.0f - mv.z) * -1e9f;
                mt[kg][3] = (1.0f - mv.w) * -1e9f;
            }

            const bool diag = (kt == ktd);

            // ---- per rg: softmax -> P write -> PV ----
#pragma unroll
            for (int rg = 0; rg < 2; rg++) {
                const int qrow = rowb + rg * 16 + ln;
                float sc[4][4];
#pragma unroll
                for (int kg = 0; kg < 4; kg++) {
                    const int keyb = base + kg * 16 + qd * 4;
#pragma unroll
                    for (int i = 0; i < 4; i++) {
                        float v = fmaf(St[rg][kg][i], 0.125f, mt[kg][i]);
                        sc[kg][i] = (diag && (keyb + i > qrow)) ? -1e30f : v;
                    }
                }
                float mx = sc[0][0];
#pragma unroll
                for (int kg = 0; kg < 4; kg++)
#pragma unroll
                    for (int i = 0; i < 4; i++) mx = fmaxf(mx, sc[kg][i]);
                mx = fmaxf(mx, __shfl_xor(mx, 16));
                mx = fmaxf(mx, __shfl_xor(mx, 32));

                // defer-max (T13): rescale only when some row moved > 8
                if (__ballot(mx > mrow[rg] + 8.0f)) {
                    float nm    = fmaxf(mrow[rg], mx);
                    float alpha = __expf(mrow[rg] - nm);
                    lrow[rg] *= alpha;
#pragma unroll
                    for (int i = 0; i < 4; i++) {
                        float av = __shfl(alpha, qd * 4 + i);
#pragma unroll
                        for (int dt = 0; dt < 4; dt++) O[rg][dt][i] *= av;
                    }
                    mrow[rg] = nm;
                }
                const float nm = mrow[rg];

                float ls = 0.0f;
#pragma unroll
                for (int kg = 0; kg < 4; kg++)
#pragma unroll
                    for (int i = 0; i < 4; i++) {
                        float p = __expf(sc[kg][i] - nm);
                        sc[kg][i] = p;
                        ls += p;
                    }
                ls += __shfl_xor(ls, 16);
                ls += __shfl_xor(ls, 32);
                lrow[rg] += ls;

#pragma unroll
                for (int kg = 0; kg < 4; kg++) {
                    short4 pk2 = { f2bf(sc[kg][0]), f2bf(sc[kg][1]),
                                   f2bf(sc[kg][2]), f2bf(sc[kg][3]) };
                    *(short4*)&ps[ln * 72 + kg * 16 + qd * 4] = pk2;
                }

                // PV: O[rg] += P[rg] @ V (same-wave LDS write->read, in order)
#pragma unroll
                for (int kc2 = 0; kc2 < 2; kc2++) {
                    bf16x8 pa = *(const bf16x8*)&ps[ln * 72 + kc2 * 32 + qd * 8];
#pragma unroll
                    for (int dt = 0; dt < 4; dt++)
                        O[rg][dt] = __builtin_amdgcn_mfma_f32_16x16x32_bf16(pa, vb[kc2][dt], O[rg][dt], 0, 0, 0);
                }
            }
        }

        // ---- write prefetched tile into the other buffer ----
        if (pf) {
            const int nxt = cur ^ 1;
            *(bf16x8*)&Ks[nxt][fr * 72 + fc] = pk;
            *(bf16x8*)&Vt[nxt][fr * 72 + fc] = pv;
            if (tid < 64) mskS[nxt][tid] = pm;
        }
        __syncthreads();
        cur ^= 1;
    }

    // ---- finalize: l replicated over qd; write bf16 into q-slice ----
#pragma unroll
    for (int rg = 0; rg < 2; rg++)
#pragma unroll
        for (int i = 0; i < 4; i++) {
            float li  = __shfl(lrow[rg], qd * 4 + i);
            float inv = 1.0f / li;
            const int row = rowb + rg * 16 + qd * 4 + i;
            short* op = qkv + (size_t)(b * S_ + row) * QKVW + h * HD_ + ln;
#pragma unroll
            for (int dt = 0; dt < 4; dt++) op[dt * 16] = f2bf(O[rg][dt][i] * inv);
        }
}

// ---------------------------------------------------------------------------
extern "C" void kernel_launch(void* const* d_in, const int* in_sizes, int n_in,
                              void* d_out, int out_size, void* d_ws, size_t ws_size,
                              hipStream_t stream) {
    const float* x     = (const float*)d_in[0];
    const float* cosb  = (const float*)d_in[1];
    const float* sinb  = (const float*)d_in[2];
    const float* maskb = (const float*)d_in[3];
    const float* Wq    = (const float*)d_in[4];
    const float* Wk    = (const float*)d_in[5];
    const float* Wv    = (const float*)d_in[6];
    const float* Wo    = (const float*)d_in[7];

    const int M = B_ * S_;   // 4096

    // ws: qkv | Wqkvt | Wot | Vtg  (19.9 MB bf16).
    // d_out doubles as scratch: xb = bf16(x) (8.4 MB of its 16.8 MB) lives
    // there until gemm2 overwrites it with the final fp32 output.
    short* qkv   = (short*)d_ws;                     // [4096][1536]
    short* Wqkvt = qkv + (size_t)M * QKVW;           // [1536][1024]
    short* Wot   = Wqkvt + (size_t)QKVW * H_;        // [1024][1024]
    short* Vtg   = Wot + (size_t)H_ * H_;            // [8*64][2048]
    short* xb    = (short*)d_out;                    // [4096][1024] bf16 scratch
    float* out   = (float*)d_out;

    dim3 blk(256);

    // transposes + x->bf16 convert
    tconv_all<<<dim3(896), blk, 0, stream>>>(Wq, Wk, Wv, Wo, Wqkvt, Wot, x, xb);

    // GEMM1 fused (128x128 tile): qkv(q,k roped) + Vtg from xb
    gemm1_fused<<<dim3(QKVW / 128, M / 128), blk, 0, stream>>>(xb, Wqkvt, qkv, Vtg, cosb, sinb);

    // attention: 256 pair-blocks x 512 threads (8 waves), uniform 132
    // wave-tiles/block, K/V staged once per block  (measured 77.5 us)
    attn_kernel<<<dim3(256), dim3(512), 0, stream>>>(qkv, Vtg, maskb);

    // GEMM2 (128x128 tile): out = attn_out(q-slice of qkv) @ Wot^T (fp32)
    gemm2_bt<<<dim3(H_ / 128, M / 128), blk, 0, stream>>>(qkv, QKVW, Wot, out, H_, H_);
}

// Round 7
// 195.036 us; speedup vs baseline: 1.0595x; 1.0595x over previous
//
#include <hip/hip_runtime.h>
#include <math.h>

#define B_   2
#define S_   2048
#define H_   1024
#define NH_  16
#define NKV_ 4
#define HD_  64
#define R_   (NH_ / NKV_)   // 4 q-heads per kv-head
#define QKVW 1536           // qkv row width (q 0..1023 | k 1024..1279 | v 1280..1535)

typedef __attribute__((ext_vector_type(8))) short bf16x8;
typedef __attribute__((ext_vector_type(4))) float f32x4;

__device__ inline short f2bf(float f) {
    unsigned u = __float_as_uint(f);
    u += 0x7FFF + ((u >> 16) & 1);     // RNE to bf16
    return (short)(u >> 16);
}

// async global->LDS, 16 B per lane; lptr is the wave-uniform chunk base,
// HW scatters lane i's 16 B at lptr + i*16 (m97/m104 semantics).
__device__ inline void gload_lds16(const void* gptr, void* lptr) {
    __builtin_amdgcn_global_load_lds(
        (const __attribute__((address_space(1))) unsigned int*)gptr,
        (__attribute__((address_space(3))) unsigned int*)lptr,
        16, 0, 0);
}

// ---------------------------------------------------------------------------
// Weight transposes + x->bf16 convert in one launch. 896 blocks:
// [0,640) = 64x64 transpose tiles (Wq/Wk/Wv/Wo); [640,896) = xb = bf16(x).
// ---------------------------------------------------------------------------
__global__ __launch_bounds__(256) void tconv_all(const float* __restrict__ Wq,
                                                 const float* __restrict__ Wk,
                                                 const float* __restrict__ Wv,
                                                 const float* __restrict__ Wo,
                                                 short* __restrict__ Wqkvt,
                                                 short* __restrict__ Wot,
                                                 const float* __restrict__ x,
                                                 short* __restrict__ xb) {
    const int bx = blockIdx.x;
    const int tid = threadIdx.x;

    if (bx >= 640) {           // ---- x -> bf16 convert ----
        const size_t e0 = (size_t)(bx - 640) * 16384;
#pragma unroll
        for (int t = 0; t < 8; t++) {
            const size_t i = e0 + ((size_t)t * 256 + tid) * 8;
            float4 a = *(const float4*)&x[i];
            float4 c = *(const float4*)&x[i + 4];
            bf16x8 o;
            o[0] = f2bf(a.x); o[1] = f2bf(a.y); o[2] = f2bf(a.z); o[3] = f2bf(a.w);
            o[4] = f2bf(c.x); o[5] = f2bf(c.y); o[6] = f2bf(c.z); o[7] = f2bf(c.w);
            *(bf16x8*)&xb[i] = o;
        }
        return;
    }

    __shared__ short T[64][68];
    const float* W; short* Wt; int N, idx;
    if (bx < 256)      { W = Wq; Wt = Wqkvt;                     N = 1024; idx = bx; }
    else if (bx < 320) { W = Wk; Wt = Wqkvt + 1024 * 1024;       N = 256;  idx = bx - 256; }
    else if (bx < 384) { W = Wv; Wt = Wqkvt + 1280 * 1024;       N = 256;  idx = bx - 320; }
    else               { W = Wo; Wt = Wot;                       N = 1024; idx = bx - 384; }
    const int ntiles = N >> 6;
    const int n0 = (idx % ntiles) * 64;
    const int k0 = (idx / ntiles) * 64;

    const int r  = tid >> 4;
    const int c4 = (tid & 15) * 4;
#pragma unroll
    for (int t = 0; t < 4; t++) {
        int row = t * 16 + r;
        float4 v = *(const float4*)&W[(size_t)(k0 + row) * N + n0 + c4];
        T[c4 + 0][row] = f2bf(v.x);
        T[c4 + 1][row] = f2bf(v.y);
        T[c4 + 2][row] = f2bf(v.z);
        T[c4 + 3][row] = f2bf(v.w);
    }
    __syncthreads();
#pragma unroll
    for (int t = 0; t < 4; t++) {
        int row = t * 16 + r;          // n index
        short4 o = *(short4*)&T[row][c4];
        *(short4*)&Wt[(size_t)(n0 + row) * 1024 + k0 + c4] = o;
    }
}

// ---------------------------------------------------------------------------
// Fused GEMM1: qkv = xb @ Wqkvt^T, 128x128 tile, BK=32, 256 threads.
// RoPE epilogue for q/k cols; v cols scattered transposed into Vtg.
// ---------------------------------------------------------------------------
__global__ __launch_bounds__(256) void gemm1_fused(const short* __restrict__ xb,
                                                   const short* __restrict__ Bt,
                                                   short* __restrict__ qkv,
                                                   short* __restrict__ Vtg,
                                                   const float* __restrict__ cosb,
                                                   const float* __restrict__ sinb) {
    __shared__ short Ah[128 * 32];   // [row][k] 8 KB
    __shared__ short Bh[128 * 32];   // [col][k] 8 KB

    const int tid  = threadIdx.x;
    const int w    = tid >> 6;
    const int lane = tid & 63;
    const int ln   = lane & 15;
    const int qd   = lane >> 4;
    const int wr   = w >> 1, wc = w & 1;
    const int row0 = blockIdx.y * 128;
    const int col0 = blockIdx.x * 128;

    const int sr = lane >> 2;        // 0..15 staging row-in-chunk
    const int sk = (lane & 3) * 8;   // k element offset

    f32x4 acc[4][4];
#pragma unroll
    for (int mi = 0; mi < 4; mi++)
#pragma unroll
        for (int ni = 0; ni < 4; ni++)
            acc[mi][ni] = (f32x4){0.f, 0.f, 0.f, 0.f};

    for (int k0 = 0; k0 < 1024; k0 += 32) {
        __syncthreads();   // previous iter's frag reads done
        gload_lds16(xb + (size_t)(row0 + w * 16 + sr) * 1024 + k0 + sk,      &Ah[(w * 16) * 32]);
        gload_lds16(xb + (size_t)(row0 + 64 + w * 16 + sr) * 1024 + k0 + sk, &Ah[(64 + w * 16) * 32]);
        gload_lds16(Bt + (size_t)(col0 + w * 16 + sr) * 1024 + k0 + sk,      &Bh[(w * 16) * 32]);
        gload_lds16(Bt + (size_t)(col0 + 64 + w * 16 + sr) * 1024 + k0 + sk, &Bh[(64 + w * 16) * 32]);
        __syncthreads();

        bf16x8 af[4], bf[4];
#pragma unroll
        for (int mi = 0; mi < 4; mi++)
            af[mi] = *(const bf16x8*)&Ah[(wr * 64 + mi * 16 + ln) * 32 + qd * 8];
#pragma unroll
        for (int ni = 0; ni < 4; ni++)
            bf[ni] = *(const bf16x8*)&Bh[(wc * 64 + ni * 16 + ln) * 32 + qd * 8];
#pragma unroll
        for (int mi = 0; mi < 4; mi++)
#pragma unroll
            for (int ni = 0; ni < 4; ni++)
                acc[mi][ni] = __builtin_amdgcn_mfma_f32_16x16x32_bf16(af[mi], bf[ni], acc[mi][ni], 0, 0, 0);
    }

    const int colw = col0 + wc * 64;          // this wave's 64-col half
    if (colw < H_ + NKV_ * HD_) {
        // ---- q or k columns: RoPE in fp32, store bf16 to qkv ----
#pragma unroll
        for (int mi = 0; mi < 4; mi++)
#pragma unroll
            for (int i = 0; i < 4; i++) {
                const int row  = row0 + wr * 64 + mi * 16 + qd * 4 + i;
                const int spos = row & (S_ - 1);
                const float* cp = cosb + (size_t)spos * HD_;
                const float* sp = sinb + (size_t)spos * HD_;
                float o0[4];
#pragma unroll
                for (int ni = 0; ni < 2; ni++) {
                    const int d = ni * 16 + ln;
                    float x0 = acc[mi][ni][i], x1 = acc[mi][ni + 2][i];
                    o0[ni]     = x0 * cp[d]      - x1 * sp[d];
                    o0[ni + 2] = x1 * cp[d + 32] + x0 * sp[d + 32];
                }
                short* Cp = qkv + (size_t)row * QKVW + colw + ln;
#pragma unroll
                for (int ni = 0; ni < 4; ni++) Cp[ni * 16] = f2bf(o0[ni]);
            }
    } else {
        // ---- v columns: transposed scatter into Vtg[(b*NKV+g)*HD+d][s] ----
        const int g = (colw - (H_ + NKV_ * HD_)) >> 6;
#pragma unroll
        for (int mi = 0; mi < 4; mi++) {
            const int rbase = row0 + wr * 64 + mi * 16 + qd * 4;   // i = +0..3
            const int bg = ((rbase >> 11) * NKV_) + g;
            const int s0 = rbase & (S_ - 1);
#pragma unroll
            for (int ni = 0; ni < 4; ni++) {
                const int d = ni * 16 + ln;
                short4 pk = { f2bf(acc[mi][ni][0]), f2bf(acc[mi][ni][1]),
                              f2bf(acc[mi][ni][2]), f2bf(acc[mi][ni][3]) };
                *(short4*)&Vtg[((size_t)bg * HD_ + d) * S_ + s0] = pk;
            }
        }
    }
}

// ---------------------------------------------------------------------------
// bf16 MFMA GEMM, B^T form: C[M,N] = A[M,K] @ Bt[N,K]^T (fp32 out).
// 128x128 tile, BK=32, 256 threads. Output projection.
// ---------------------------------------------------------------------------
__global__ __launch_bounds__(256) void gemm2_bt(const short* __restrict__ A, int lda,
                                                const short* __restrict__ Bt,
                                                float* __restrict__ C, int ldc,
                                                int K) {
    __shared__ short Ah[128 * 32];
    __shared__ short Bh[128 * 32];

    const int tid  = threadIdx.x;
    const int w    = tid >> 6;
    const int lane = tid & 63;
    const int ln   = lane & 15;
    const int qd   = lane >> 4;
    const int wr   = w >> 1, wc = w & 1;
    const int row0 = blockIdx.y * 128;
    const int col0 = blockIdx.x * 128;

    const int sr = lane >> 2;
    const int sk = (lane & 3) * 8;

    f32x4 acc[4][4];
#pragma unroll
    for (int mi = 0; mi < 4; mi++)
#pragma unroll
        for (int ni = 0; ni < 4; ni++)
            acc[mi][ni] = (f32x4){0.f, 0.f, 0.f, 0.f};

    for (int k0 = 0; k0 < K; k0 += 32) {
        __syncthreads();
        gload_lds16(A + (size_t)(row0 + w * 16 + sr) * lda + k0 + sk,      &Ah[(w * 16) * 32]);
        gload_lds16(A + (size_t)(row0 + 64 + w * 16 + sr) * lda + k0 + sk, &Ah[(64 + w * 16) * 32]);
        gload_lds16(Bt + (size_t)(col0 + w * 16 + sr) * K + k0 + sk,       &Bh[(w * 16) * 32]);
        gload_lds16(Bt + (size_t)(col0 + 64 + w * 16 + sr) * K + k0 + sk,  &Bh[(64 + w * 16) * 32]);
        __syncthreads();

        bf16x8 af[4], bf[4];
#pragma unroll
        for (int mi = 0; mi < 4; mi++)
            af[mi] = *(const bf16x8*)&Ah[(wr * 64 + mi * 16 + ln) * 32 + qd * 8];
#pragma unroll
        for (int ni = 0; ni < 4; ni++)
            bf[ni] = *(const bf16x8*)&Bh[(wc * 64 + ni * 16 + ln) * 32 + qd * 8];
#pragma unroll
        for (int mi = 0; mi < 4; mi++)
#pragma unroll
            for (int ni = 0; ni < 4; ni++)
                acc[mi][ni] = __builtin_amdgcn_mfma_f32_16x16x32_bf16(af[mi], bf[ni], acc[mi][ni], 0, 0, 0);
    }

#pragma unroll
    for (int mi = 0; mi < 4; mi++)
#pragma unroll
        for (int i = 0; i < 4; i++) {
            const size_t row = row0 + wr * 64 + mi * 16 + qd * 4 + i;
            float* Cp = C + row * ldc + col0 + wc * 64 + ln;
#pragma unroll
            for (int ni = 0; ni < 4; ni++) Cp[ni * 16] = acc[mi][ni][i];
        }
}

// ---------------------------------------------------------------------------
// bf16 MFMA flash attention v16: uniform 34-step pair-blocks, dense waves.
//   v15 post-mortem: avg occupancy 17.6/25 -> ~30% inter-block step
//   imbalance (nt = 32-2a); worse, a=0 blocks ran 30 of 32 steps with 4/8
//   waves compute-idle (1 wave/SIMD exposed latency) — measured critical
//   path = 32 x 5400cy = 71us. v16: the pair's two q-tiles run as two
//   SEQUENTIAL phases; each phase all 8 waves take 16-row strips of ONE
//   q-tile. Steps = (2a+2) + (32-2a) = 34 for EVERY block, every step
//   ~8 compute-dense waves (2/SIMD). Per-wave softmax halves (one rg).
//   Mask bias pre-computed in staging ((1-m)*-1e9 stored in mskS).
//   Staging/prefetch/barrier structure unchanged from v15 (proven).
// ---------------------------------------------------------------------------
__global__ __launch_bounds__(512, 2) void attn_kernel(short* __restrict__ qkv,
                                                      const short* __restrict__ Vtg,
                                                      const float* __restrict__ maskb) {
    const int tid  = threadIdx.x;
    const int w    = tid >> 6;           // 0..7
    const int lane = tid & 63;
    const int ln   = lane & 15;
    const int qd   = lane >> 4;

    // fid&7 = bg -> XCD affinity for the K/V slice
    const int fid = blockIdx.x;          // 0..255
    const int bg  = fid & 7;             // b*NKV+g
    const int u   = fid >> 3;            // 0..31
    const int b   = bg >> 2;
    const int g   = bg & 3;
    const int h   = g * R_ + (u & 3);
    const int a   = u >> 2;              // pair index 0..7

    __shared__ short Ks[2][64 * 72];     // K  [key][dim], stride 72
    __shared__ short Vt[2][64 * 72];     // V^T [dim][key]
    __shared__ short Ps[8][16 * 72];     // per-wave P round-trip
    __shared__ float mskS[2][64];        // PRE-BIASED: (1-m)*-1e9
    short* const ps = Ps[w];

    const short* const Kb = qkv + (size_t)b * S_ * QKVW + H_ + g * HD_;
    const short* const Vb = Vtg + (size_t)bg * HD_ * S_;
    const float* const mb = maskb + b * S_;

    const int fr = tid >> 3;             // 0..63 (staging row)
    const int fc = (tid & 7) * 8;        // staging col (elements)

#pragma unroll 1
    for (int ph = 0; ph < 2; ph++) {
        const int qt   = ph ? (15 - a) : a;
        const int rowb = qt * 128 + w * 16;   // this wave's 16-row strip
        const int ktd  = 2 * qt + (w >> 2);   // wave's diagonal tile
        const int ntp  = 2 * qt + 2;          // tiles this phase
        const int qrow = rowb + ln;

        // ---- Q B-frags: rows rowb+ln ----
        bf16x8 qf0, qf1;
        {
            const short* qp = qkv + (size_t)(b * S_ + rowb + ln) * QKVW + h * HD_;
            qf0 = *(const bf16x8*)&qp[qd * 8];
            qf1 = *(const bf16x8*)&qp[32 + qd * 8];
        }

        f32x4 O[4] = {};
        float mrow = -1e30f, lrow = 0.0f;

        // ---- stage tile 0 ----
        *(bf16x8*)&Ks[0][fr * 72 + fc] = *(const bf16x8*)&Kb[(size_t)fr * QKVW + fc];
        *(bf16x8*)&Vt[0][fr * 72 + fc] = *(const bf16x8*)&Vb[(size_t)fr * S_ + fc];
        if (tid < 64) mskS[0][tid] = (1.0f - mb[tid]) * -1e9f;
        __syncthreads();

        int cur = 0;
#pragma unroll 1
        for (int kt = 0; kt < ntp; kt++) {
            const int base = kt * 64;
            const bool pf = (kt + 1 < ntp);

            // ---- prefetch tile kt+1 into registers (no wait) ----
            bf16x8 pk, pv;
            float pm = 0.0f;
            if (pf) {
                const int nb = base + 64;
                pk = *(const bf16x8*)&Kb[(size_t)(nb + fr) * QKVW + fc];
                pv = *(const bf16x8*)&Vb[(size_t)fr * S_ + nb + fc];
                if (tid < 64) pm = (1.0f - mb[nb + tid]) * -1e9f;
            }

            if (kt <= ktd) {   // wave-uniform
                // ---- QK^T swapped: St[kg] = S^T[key][qrow=ln] ----
                f32x4 St[4];
#pragma unroll
                for (int kg = 0; kg < 4; kg++) {
                    bf16x8 ka0 = *(const bf16x8*)&Ks[cur][(kg * 16 + ln) * 72 + qd * 8];
                    bf16x8 ka1 = *(const bf16x8*)&Ks[cur][(kg * 16 + ln) * 72 + 32 + qd * 8];
                    f32x4 z = {0.f, 0.f, 0.f, 0.f};
                    z = __builtin_amdgcn_mfma_f32_16x16x32_bf16(ka0, qf0, z, 0, 0, 0);
                    St[kg] = __builtin_amdgcn_mfma_f32_16x16x32_bf16(ka1, qf1, z, 0, 0, 0);
                }

                // ---- V B-frags from LDS ----
                bf16x8 vb[2][4];
#pragma unroll
                for (int kc2 = 0; kc2 < 2; kc2++)
#pragma unroll
                    for (int dt = 0; dt < 4; dt++)
                        vb[kc2][dt] = *(const bf16x8*)&Vt[cur][(dt * 16 + ln) * 72 + kc2 * 32 + qd * 8];

                // ---- scale + pre-biased mask; causal only on diag tile ----
                float sc[4][4];
#pragma unroll
                for (int kg = 0; kg < 4; kg++) {
                    float4 mv = *(const float4*)&mskS[cur][kg * 16 + qd * 4];
                    sc[kg][0] = fmaf(St[kg][0], 0.125f, mv.x);
                    sc[kg][1] = fmaf(St[kg][1], 0.125f, mv.y);
                    sc[kg][2] = fmaf(St[kg][2], 0.125f, mv.z);
                    sc[kg][3] = fmaf(St[kg][3], 0.125f, mv.w);
                }
                if (kt == ktd) {
#pragma unroll
                    for (int kg = 0; kg < 4; kg++) {
                        const int keyb = base + kg * 16 + qd * 4;
#pragma unroll
                        for (int i = 0; i < 4; i++)
                            if (keyb + i > qrow) sc[kg][i] = -1e30f;
                    }
                }

                float mx = sc[0][0];
#pragma unroll
                for (int kg = 0; kg < 4; kg++)
#pragma unroll
                    for (int i = 0; i < 4; i++) mx = fmaxf(mx, sc[kg][i]);
                mx = fmaxf(mx, __shfl_xor(mx, 16));
                mx = fmaxf(mx, __shfl_xor(mx, 32));

                // defer-max (T13): rescale only when some row moved > 8
                if (__ballot(mx > mrow + 8.0f)) {
                    float nm    = fmaxf(mrow, mx);
                    float alpha = __expf(mrow - nm);
                    lrow *= alpha;
#pragma unroll
                    for (int i = 0; i < 4; i++) {
                        float av = __shfl(alpha, qd * 4 + i);
#pragma unroll
                        for (int dt = 0; dt < 4; dt++) O[dt][i] *= av;
                    }
                    mrow = nm;
                }
                const float nm = mrow;

                float ls = 0.0f;
#pragma unroll
                for (int kg = 0; kg < 4; kg++)
#pragma unroll
                    for (int i = 0; i < 4; i++) {
                        float p = __expf(sc[kg][i] - nm);
                        sc[kg][i] = p;
                        ls += p;
                    }
                ls += __shfl_xor(ls, 16);
                ls += __shfl_xor(ls, 32);
                lrow += ls;

#pragma unroll
                for (int kg = 0; kg < 4; kg++) {
                    short4 pko = { f2bf(sc[kg][0]), f2bf(sc[kg][1]),
                                   f2bf(sc[kg][2]), f2bf(sc[kg][3]) };
                    *(short4*)&ps[ln * 72 + kg * 16 + qd * 4] = pko;
                }

                // ---- PV: O += P @ V (same-wave LDS write->read) ----
#pragma unroll
                for (int kc2 = 0; kc2 < 2; kc2++) {
                    bf16x8 pa = *(const bf16x8*)&ps[ln * 72 + kc2 * 32 + qd * 8];
#pragma unroll
                    for (int dt = 0; dt < 4; dt++)
                        O[dt] = __builtin_amdgcn_mfma_f32_16x16x32_bf16(pa, vb[kc2][dt], O[dt], 0, 0, 0);
                }
            }

            // ---- write prefetched tile into the other buffer ----
            if (pf) {
                const int nxt = cur ^ 1;
                *(bf16x8*)&Ks[nxt][fr * 72 + fc] = pk;
                *(bf16x8*)&Vt[nxt][fr * 72 + fc] = pv;
                if (tid < 64) mskS[nxt][tid] = pm;
            }
            __syncthreads();
            cur ^= 1;
        }

        // ---- finalize this phase: write bf16 into q-slice ----
        // (rows written here are q-tile qt; phase 2 reads q-tile 15-a —
        //  disjoint, and all compute reads of Ks/Vt ended before the loop's
        //  final barrier, so phase-2 restaging is race-free.)
#pragma unroll
        for (int i = 0; i < 4; i++) {
            float li  = __shfl(lrow, qd * 4 + i);
            float inv = 1.0f / li;
            const int row = rowb + qd * 4 + i;
            short* op = qkv + (size_t)(b * S_ + row) * QKVW + h * HD_ + ln;
#pragma unroll
            for (int dt = 0; dt < 4; dt++) op[dt * 16] = f2bf(O[dt][i] * inv);
        }
    }
}

// ---------------------------------------------------------------------------
extern "C" void kernel_launch(void* const* d_in, const int* in_sizes, int n_in,
                              void* d_out, int out_size, void* d_ws, size_t ws_size,
                              hipStream_t stream) {
    const float* x     = (const float*)d_in[0];
    const float* cosb  = (const float*)d_in[1];
    const float* sinb  = (const float*)d_in[2];
    const float* maskb = (const float*)d_in[3];
    const float* Wq    = (const float*)d_in[4];
    const float* Wk    = (const float*)d_in[5];
    const float* Wv    = (const float*)d_in[6];
    const float* Wo    = (const float*)d_in[7];

    const int M = B_ * S_;   // 4096

    // ws: qkv | Wqkvt | Wot | Vtg  (19.9 MB bf16).
    // d_out doubles as scratch: xb = bf16(x) lives there until gemm2
    // overwrites it with the final fp32 output.
    short* qkv   = (short*)d_ws;                     // [4096][1536]
    short* Wqkvt = qkv + (size_t)M * QKVW;           // [1536][1024]
    short* Wot   = Wqkvt + (size_t)QKVW * H_;        // [1024][1024]
    short* Vtg   = Wot + (size_t)H_ * H_;            // [8*64][2048]
    short* xb    = (short*)d_out;                    // [4096][1024] bf16 scratch
    float* out   = (float*)d_out;

    dim3 blk(256);

    // transposes + x->bf16 convert
    tconv_all<<<dim3(896), blk, 0, stream>>>(Wq, Wk, Wv, Wo, Wqkvt, Wot, x, xb);

    // GEMM1 fused (128x128 tile): qkv(q,k roped) + Vtg from xb
    gemm1_fused<<<dim3(QKVW / 128, M / 128), blk, 0, stream>>>(xb, Wqkvt, qkv, Vtg, cosb, sinb);

    // attention: 256 pair-blocks x 512 threads, uniform 34 steps/block
    attn_kernel<<<dim3(256), dim3(512), 0, stream>>>(qkv, Vtg, maskb);

    // GEMM2 (128x128 tile): out = attn_out(q-slice of qkv) @ Wot^T (fp32)
    gemm2_bt<<<dim3(H_ / 128, M / 128), blk, 0, stream>>>(qkv, QKVW, Wot, out, H_, H_);
}

// Round 8
// 184.385 us; speedup vs baseline: 1.1207x; 1.0578x over previous
//
#include <hip/hip_runtime.h>
#include <math.h>

#define B_   2
#define S_   2048
#define H_   1024
#define NH_  16
#define NKV_ 4
#define HD_  64
#define R_   (NH_ / NKV_)   // 4 q-heads per kv-head
#define QKVW 1536           // qkv row width (q 0..1023 | k 1024..1279 | v 1280..1535)

typedef __attribute__((ext_vector_type(8))) short bf16x8;
typedef __attribute__((ext_vector_type(4))) float f32x4;

__device__ inline short f2bf(float f) {
    unsigned u = __float_as_uint(f);
    u += 0x7FFF + ((u >> 16) & 1);     // RNE to bf16
    return (short)(u >> 16);
}

// native 2^x (v_exp_f32). Builtin if available (compiler handles trans-op
// hazards); asm fallback carries its own s_nop wait-state.
__device__ inline float exp2fast(float x) {
#if __has_builtin(__builtin_amdgcn_exp2f)
    return __builtin_amdgcn_exp2f(x);
#else
    float r; asm volatile("v_exp_f32 %0, %1\n\ts_nop 1" : "=v"(r) : "v"(x)); return r;
#endif
}

// pack 2 fp32 -> 2 bf16 (RNE) in one instr (T12 recipe; no builtin on gfx950)
__device__ inline unsigned cvt_pk_bf16(float lo, float hi) {
    unsigned r;
    asm("v_cvt_pk_bf16_f32 %0, %1, %2" : "=v"(r) : "v"(lo), "v"(hi));
    return r;
}

#define LOG2E 1.4426950408889634f

// async global->LDS, 16 B per lane; lptr is the wave-uniform chunk base,
// HW scatters lane i's 16 B at lptr + i*16 (m97/m104 semantics).
__device__ inline void gload_lds16(const void* gptr, void* lptr) {
    __builtin_amdgcn_global_load_lds(
        (const __attribute__((address_space(1))) unsigned int*)gptr,
        (__attribute__((address_space(3))) unsigned int*)lptr,
        16, 0, 0);
}

// ---------------------------------------------------------------------------
// Weight transposes + x->bf16 convert in one launch. 896 blocks:
// [0,640) = 64x64 transpose tiles (Wq/Wk/Wv/Wo); [640,896) = xb = bf16(x).
// ---------------------------------------------------------------------------
__global__ __launch_bounds__(256) void tconv_all(const float* __restrict__ Wq,
                                                 const float* __restrict__ Wk,
                                                 const float* __restrict__ Wv,
                                                 const float* __restrict__ Wo,
                                                 short* __restrict__ Wqkvt,
                                                 short* __restrict__ Wot,
                                                 const float* __restrict__ x,
                                                 short* __restrict__ xb) {
    const int bx = blockIdx.x;
    const int tid = threadIdx.x;

    if (bx >= 640) {           // ---- x -> bf16 convert ----
        const size_t e0 = (size_t)(bx - 640) * 16384;
#pragma unroll
        for (int t = 0; t < 8; t++) {
            const size_t i = e0 + ((size_t)t * 256 + tid) * 8;
            float4 a = *(const float4*)&x[i];
            float4 c = *(const float4*)&x[i + 4];
            bf16x8 o;
            o[0] = f2bf(a.x); o[1] = f2bf(a.y); o[2] = f2bf(a.z); o[3] = f2bf(a.w);
            o[4] = f2bf(c.x); o[5] = f2bf(c.y); o[6] = f2bf(c.z); o[7] = f2bf(c.w);
            *(bf16x8*)&xb[i] = o;
        }
        return;
    }

    __shared__ short T[64][68];
    const float* W; short* Wt; int N, idx;
    if (bx < 256)      { W = Wq; Wt = Wqkvt;                     N = 1024; idx = bx; }
    else if (bx < 320) { W = Wk; Wt = Wqkvt + 1024 * 1024;       N = 256;  idx = bx - 256; }
    else if (bx < 384) { W = Wv; Wt = Wqkvt + 1280 * 1024;       N = 256;  idx = bx - 320; }
    else               { W = Wo; Wt = Wot;                       N = 1024; idx = bx - 384; }
    const int ntiles = N >> 6;
    const int n0 = (idx % ntiles) * 64;
    const int k0 = (idx / ntiles) * 64;

    const int r  = tid >> 4;
    const int c4 = (tid & 15) * 4;
#pragma unroll
    for (int t = 0; t < 4; t++) {
        int row = t * 16 + r;
        float4 v = *(const float4*)&W[(size_t)(k0 + row) * N + n0 + c4];
        T[c4 + 0][row] = f2bf(v.x);
        T[c4 + 1][row] = f2bf(v.y);
        T[c4 + 2][row] = f2bf(v.z);
        T[c4 + 3][row] = f2bf(v.w);
    }
    __syncthreads();
#pragma unroll
    for (int t = 0; t < 4; t++) {
        int row = t * 16 + r;          // n index
        short4 o = *(short4*)&T[row][c4];
        *(short4*)&Wt[(size_t)(n0 + row) * 1024 + k0 + c4] = o;
    }
}

// ---------------------------------------------------------------------------
// Fused GEMM1 v3: qkv = xb @ Wqkvt^T, 64x128 tile, BK=32, glds staging.
// 768 blocks = exactly 3 rounds at 3 co-resident blocks/CU (12 KB LDS):
// cross-block waves hide the per-iter barrier drain (m97 mechanism) —
// the 128^2 version's 384-block grid left round 2 half-idle.
// RoPE epilogue for q/k cols; v cols scattered transposed into Vtg.
// ---------------------------------------------------------------------------
__global__ __launch_bounds__(256) void gemm1_fused(const short* __restrict__ xb,
                                                   const short* __restrict__ Bt,
                                                   short* __restrict__ qkv,
                                                   short* __restrict__ Vtg,
                                                   const float* __restrict__ cosb,
                                                   const float* __restrict__ sinb) {
    __shared__ short Ah[64 * 32];    // [row][k] 4 KB
    __shared__ short Bh[128 * 32];   // [col][k] 8 KB

    const int tid  = threadIdx.x;
    const int w    = tid >> 6;
    const int lane = tid & 63;
    const int ln   = lane & 15;
    const int qd   = lane >> 4;
    const int wr   = w >> 1, wc = w & 1;
    const int row0 = blockIdx.y * 64;
    const int col0 = blockIdx.x * 128;

    const int sr = lane >> 2;        // 0..15 staging row-in-chunk
    const int sk = (lane & 3) * 8;   // k element offset

    f32x4 acc[2][4];
#pragma unroll
    for (int mi = 0; mi < 2; mi++)
#pragma unroll
        for (int ni = 0; ni < 4; ni++)
            acc[mi][ni] = (f32x4){0.f, 0.f, 0.f, 0.f};

    for (int k0 = 0; k0 < 1024; k0 += 32) {
        __syncthreads();   // previous iter's frag reads done
        gload_lds16(xb + (size_t)(row0 + w * 16 + sr) * 1024 + k0 + sk,      &Ah[(w * 16) * 32]);
        gload_lds16(Bt + (size_t)(col0 + w * 32 + sr) * 1024 + k0 + sk,      &Bh[(w * 32) * 32]);
        gload_lds16(Bt + (size_t)(col0 + w * 32 + 16 + sr) * 1024 + k0 + sk, &Bh[(w * 32 + 16) * 32]);
        __syncthreads();

        bf16x8 af[2], bfr[4];
#pragma unroll
        for (int mi = 0; mi < 2; mi++)
            af[mi] = *(const bf16x8*)&Ah[(wr * 32 + mi * 16 + ln) * 32 + qd * 8];
#pragma unroll
        for (int ni = 0; ni < 4; ni++)
            bfr[ni] = *(const bf16x8*)&Bh[(wc * 64 + ni * 16 + ln) * 32 + qd * 8];
#pragma unroll
        for (int mi = 0; mi < 2; mi++)
#pragma unroll
            for (int ni = 0; ni < 4; ni++)
                acc[mi][ni] = __builtin_amdgcn_mfma_f32_16x16x32_bf16(af[mi], bfr[ni], acc[mi][ni], 0, 0, 0);
    }

    const int colw = col0 + wc * 64;          // this wave's 64-col half
    if (colw < H_ + NKV_ * HD_) {
        // ---- q or k columns: RoPE in fp32, store bf16 to qkv ----
#pragma unroll
        for (int mi = 0; mi < 2; mi++)
#pragma unroll
            for (int i = 0; i < 4; i++) {
                const int row  = row0 + wr * 32 + mi * 16 + qd * 4 + i;
                const int spos = row & (S_ - 1);
                const float* cp = cosb + (size_t)spos * HD_;
                const float* sp = sinb + (size_t)spos * HD_;
                float o0[4];
#pragma unroll
                for (int ni = 0; ni < 2; ni++) {
                    const int d = ni * 16 + ln;
                    float x0 = acc[mi][ni][i], x1 = acc[mi][ni + 2][i];
                    o0[ni]     = x0 * cp[d]      - x1 * sp[d];
                    o0[ni + 2] = x1 * cp[d + 32] + x0 * sp[d + 32];
                }
                short* Cp = qkv + (size_t)row * QKVW + colw + ln;
#pragma unroll
                for (int ni = 0; ni < 4; ni++) Cp[ni * 16] = f2bf(o0[ni]);
            }
    } else {
        // ---- v columns: transposed scatter into Vtg[(b*NKV+g)*HD+d][s] ----
        const int g = (colw - (H_ + NKV_ * HD_)) >> 6;
#pragma unroll
        for (int mi = 0; mi < 2; mi++) {
            const int rbase = row0 + wr * 32 + mi * 16 + qd * 4;   // i = +0..3
            const int bg = ((rbase >> 11) * NKV_) + g;
            const int s0 = rbase & (S_ - 1);
#pragma unroll
            for (int ni = 0; ni < 4; ni++) {
                const int d = ni * 16 + ln;
                short4 pk = { f2bf(acc[mi][ni][0]), f2bf(acc[mi][ni][1]),
                              f2bf(acc[mi][ni][2]), f2bf(acc[mi][ni][3]) };
                *(short4*)&Vtg[((size_t)bg * HD_ + d) * S_ + s0] = pk;
            }
        }
    }
}

// ---------------------------------------------------------------------------
// bf16 MFMA GEMM, B^T form: C[M,N] = A[M,K] @ Bt[N,K]^T (fp32 out).
// 64x128 tile, BK=32, glds staging. 512 blocks = exactly 2 rounds at
// 2-3 co-resident blocks/CU. Output projection.
// ---------------------------------------------------------------------------
__global__ __launch_bounds__(256) void gemm2_bt(const short* __restrict__ A, int lda,
                                                const short* __restrict__ Bt,
                                                float* __restrict__ C, int ldc,
                                                int K) {
    __shared__ short Ah[64 * 32];
    __shared__ short Bh[128 * 32];

    const int tid  = threadIdx.x;
    const int w    = tid >> 6;
    const int lane = tid & 63;
    const int ln   = lane & 15;
    const int qd   = lane >> 4;
    const int wr   = w >> 1, wc = w & 1;
    const int row0 = blockIdx.y * 64;
    const int col0 = blockIdx.x * 128;

    const int sr = lane >> 2;
    const int sk = (lane & 3) * 8;

    f32x4 acc[2][4];
#pragma unroll
    for (int mi = 0; mi < 2; mi++)
#pragma unroll
        for (int ni = 0; ni < 4; ni++)
            acc[mi][ni] = (f32x4){0.f, 0.f, 0.f, 0.f};

    for (int k0 = 0; k0 < K; k0 += 32) {
        __syncthreads();
        gload_lds16(A + (size_t)(row0 + w * 16 + sr) * lda + k0 + sk, &Ah[(w * 16) * 32]);
        gload_lds16(Bt + (size_t)(col0 + w * 32 + sr) * K + k0 + sk, &Bh[(w * 32) * 32]);
        gload_lds16(Bt + (size_t)(col0 + w * 32 + 16 + sr) * K + k0 + sk, &Bh[(w * 32 + 16) * 32]);
        __syncthreads();

        bf16x8 af[2], bfr[4];
#pragma unroll
        for (int mi = 0; mi < 2; mi++)
            af[mi] = *(const bf16x8*)&Ah[(wr * 32 + mi * 16 + ln) * 32 + qd * 8];
#pragma unroll
        for (int ni = 0; ni < 4; ni++)
            bfr[ni] = *(const bf16x8*)&Bh[(wc * 64 + ni * 16 + ln) * 32 + qd * 8];
#pragma unroll
        for (int mi = 0; mi < 2; mi++)
#pragma unroll
            for (int ni = 0; ni < 4; ni++)
                acc[mi][ni] = __builtin_amdgcn_mfma_f32_16x16x32_bf16(af[mi], bfr[ni], acc[mi][ni], 0, 0, 0);
    }

#pragma unroll
    for (int mi = 0; mi < 2; mi++)
#pragma unroll
        for (int i = 0; i < 4; i++) {
            const size_t row = row0 + wr * 32 + mi * 16 + qd * 4 + i;
            float* Cp = C + row * ldc + col0 + wc * 64 + ln;
#pragma unroll
            for (int ni = 0; ni < 4; ni++) Cp[ni * 16] = acc[mi][ni][i];
        }
}

// ---------------------------------------------------------------------------
// bf16 MFMA flash attention v17 = v16 structure + VALU diet:
//   - softmax in log2 domain: scale = 0.125*log2e folded into QK, mask bias
//     pre-scaled by log2e in staging, p = exp2(sc-nm) via native v_exp_f32
//     (kills the 16 v_mul/step hidden in __expf); defer-max threshold
//     8 ln-units = 11.5416 log2-units.
//   - P->bf16 pack via v_cvt_pk_bf16_f32 (8 instrs vs ~64 integer-RNE ops).
//   Structure (uniform 34-step pair-blocks, staging, barriers) unchanged.
// ---------------------------------------------------------------------------
__global__ __launch_bounds__(512, 2) void attn_kernel(short* __restrict__ qkv,
                                                      const short* __restrict__ Vtg,
                                                      const float* __restrict__ maskb) {
    const int tid  = threadIdx.x;
    const int w    = tid >> 6;           // 0..7
    const int lane = tid & 63;
    const int ln   = lane & 15;
    const int qd   = lane >> 4;

    // fid&7 = bg -> XCD affinity for the K/V slice
    const int fid = blockIdx.x;          // 0..255
    const int bg  = fid & 7;             // b*NKV+g
    const int u   = fid >> 3;            // 0..31
    const int b   = bg >> 2;
    const int g   = bg & 3;
    const int h   = g * R_ + (u & 3);
    const int a   = u >> 2;              // pair index 0..7

    __shared__ short Ks[2][64 * 72];     // K  [key][dim], stride 72
    __shared__ short Vt[2][64 * 72];     // V^T [dim][key]
    __shared__ short Ps[8][16 * 72];     // per-wave P round-trip
    __shared__ float mskS[2][64];        // PRE-BIASED+SCALED: (1-m)*-1e9*log2e
    short* const ps = Ps[w];

    const short* const Kb = qkv + (size_t)b * S_ * QKVW + H_ + g * HD_;
    const short* const Vb = Vtg + (size_t)bg * HD_ * S_;
    const float* const mb = maskb + b * S_;

    const int fr = tid >> 3;             // 0..63 (staging row)
    const int fc = (tid & 7) * 8;        // staging col (elements)

#pragma unroll 1
    for (int ph = 0; ph < 2; ph++) {
        const int qt   = ph ? (15 - a) : a;
        const int rowb = qt * 128 + w * 16;   // this wave's 16-row strip
        const int ktd  = 2 * qt + (w >> 2);   // wave's diagonal tile
        const int ntp  = 2 * qt + 2;          // tiles this phase
        const int qrow = rowb + ln;

        // ---- Q B-frags: rows rowb+ln ----
        bf16x8 qf0, qf1;
        {
            const short* qp = qkv + (size_t)(b * S_ + rowb + ln) * QKVW + h * HD_;
            qf0 = *(const bf16x8*)&qp[qd * 8];
            qf1 = *(const bf16x8*)&qp[32 + qd * 8];
        }

        f32x4 O[4] = {};
        float mrow = -1e30f, lrow = 0.0f;    // mrow in log2 units

        // ---- stage tile 0 ----
        *(bf16x8*)&Ks[0][fr * 72 + fc] = *(const bf16x8*)&Kb[(size_t)fr * QKVW + fc];
        *(bf16x8*)&Vt[0][fr * 72 + fc] = *(const bf16x8*)&Vb[(size_t)fr * S_ + fc];
        if (tid < 64) mskS[0][tid] = (1.0f - mb[tid]) * (-1e9f * LOG2E);
        __syncthreads();

        int cur = 0;
#pragma unroll 1
        for (int kt = 0; kt < ntp; kt++) {
            const int base = kt * 64;
            const bool pf = (kt + 1 < ntp);

            // ---- prefetch tile kt+1 into registers (no wait) ----
            bf16x8 pk, pv;
            float pm = 0.0f;
            if (pf) {
                const int nb = base + 64;
                pk = *(const bf16x8*)&Kb[(size_t)(nb + fr) * QKVW + fc];
                pv = *(const bf16x8*)&Vb[(size_t)fr * S_ + nb + fc];
                if (tid < 64) pm = (1.0f - mb[nb + tid]) * (-1e9f * LOG2E);
            }

            if (kt <= ktd) {   // wave-uniform
                // ---- QK^T swapped: St[kg] = S^T[key][qrow=ln] ----
                f32x4 St[4];
#pragma unroll
                for (int kg = 0; kg < 4; kg++) {
                    bf16x8 ka0 = *(const bf16x8*)&Ks[cur][(kg * 16 + ln) * 72 + qd * 8];
                    bf16x8 ka1 = *(const bf16x8*)&Ks[cur][(kg * 16 + ln) * 72 + 32 + qd * 8];
                    f32x4 z = {0.f, 0.f, 0.f, 0.f};
                    z = __builtin_amdgcn_mfma_f32_16x16x32_bf16(ka0, qf0, z, 0, 0, 0);
                    St[kg] = __builtin_amdgcn_mfma_f32_16x16x32_bf16(ka1, qf1, z, 0, 0, 0);
                }

                // ---- V B-frags from LDS ----
                bf16x8 vb[2][4];
#pragma unroll
                for (int kc2 = 0; kc2 < 2; kc2++)
#pragma unroll
                    for (int dt = 0; dt < 4; dt++)
                        vb[kc2][dt] = *(const bf16x8*)&Vt[cur][(dt * 16 + ln) * 72 + kc2 * 32 + qd * 8];

                // ---- log2-domain scale + pre-scaled mask; causal on diag ----
                float sc[4][4];
#pragma unroll
                for (int kg = 0; kg < 4; kg++) {
                    float4 mv = *(const float4*)&mskS[cur][kg * 16 + qd * 4];
                    sc[kg][0] = fmaf(St[kg][0], 0.125f * LOG2E, mv.x);
                    sc[kg][1] = fmaf(St[kg][1], 0.125f * LOG2E, mv.y);
                    sc[kg][2] = fmaf(St[kg][2], 0.125f * LOG2E, mv.z);
                    sc[kg][3] = fmaf(St[kg][3], 0.125f * LOG2E, mv.w);
                }
                if (kt == ktd) {
#pragma unroll
                    for (int kg = 0; kg < 4; kg++) {
                        const int keyb = base + kg * 16 + qd * 4;
#pragma unroll
                        for (int i = 0; i < 4; i++)
                            if (keyb + i > qrow) sc[kg][i] = -1e30f;
                    }
                }

                float mx = sc[0][0];
#pragma unroll
                for (int kg = 0; kg < 4; kg++)
#pragma unroll
                    for (int i = 0; i < 4; i++) mx = fmaxf(mx, sc[kg][i]);
                mx = fmaxf(mx, __shfl_xor(mx, 16));
                mx = fmaxf(mx, __shfl_xor(mx, 32));

                // defer-max (T13): 8 ln-units = 11.5416 log2-units
                if (__ballot(mx > mrow + 11.5416f)) {
                    float nm    = fmaxf(mrow, mx);
                    float alpha = exp2fast(mrow - nm);
                    lrow *= alpha;
#pragma unroll
                    for (int i = 0; i < 4; i++) {
                        float av = __shfl(alpha, qd * 4 + i);
#pragma unroll
                        for (int dt = 0; dt < 4; dt++) O[dt][i] *= av;
                    }
                    mrow = nm;
                }
                const float nm = mrow;

                float ls = 0.0f;
#pragma unroll
                for (int kg = 0; kg < 4; kg++)
#pragma unroll
                    for (int i = 0; i < 4; i++) {
                        float p = exp2fast(sc[kg][i] - nm);
                        sc[kg][i] = p;
                        ls += p;
                    }
                ls += __shfl_xor(ls, 16);
                ls += __shfl_xor(ls, 32);
                lrow += ls;

                // ---- P pack via cvt_pk (2 f32 -> 1 u32 of 2 bf16) ----
#pragma unroll
                for (int kg = 0; kg < 4; kg++) {
                    uint2 pw;
                    pw.x = cvt_pk_bf16(sc[kg][0], sc[kg][1]);
                    pw.y = cvt_pk_bf16(sc[kg][2], sc[kg][3]);
                    *(uint2*)&ps[ln * 72 + kg * 16 + qd * 4] = pw;
                }

                // ---- PV: O += P @ V (same-wave LDS write->read) ----
#pragma unroll
                for (int kc2 = 0; kc2 < 2; kc2++) {
                    bf16x8 pa = *(const bf16x8*)&ps[ln * 72 + kc2 * 32 + qd * 8];
#pragma unroll
                    for (int dt = 0; dt < 4; dt++)
                        O[dt] = __builtin_amdgcn_mfma_f32_16x16x32_bf16(pa, vb[kc2][dt], O[dt], 0, 0, 0);
                }
            }

            // ---- write prefetched tile into the other buffer ----
            if (pf) {
                const int nxt = cur ^ 1;
                *(bf16x8*)&Ks[nxt][fr * 72 + fc] = pk;
                *(bf16x8*)&Vt[nxt][fr * 72 + fc] = pv;
                if (tid < 64) mskS[nxt][tid] = pm;
            }
            __syncthreads();
            cur ^= 1;
        }

        // ---- finalize this phase: write bf16 into q-slice ----
#pragma unroll
        for (int i = 0; i < 4; i++) {
            float li  = __shfl(lrow, qd * 4 + i);
            float inv = 1.0f / li;
            const int row = rowb + qd * 4 + i;
            short* op = qkv + (size_t)(b * S_ + row) * QKVW + h * HD_ + ln;
#pragma unroll
            for (int dt = 0; dt < 4; dt++) op[dt * 16] = f2bf(O[dt][i] * inv);
        }
    }
}

// ---------------------------------------------------------------------------
extern "C" void kernel_launch(void* const* d_in, const int* in_sizes, int n_in,
                              void* d_out, int out_size, void* d_ws, size_t ws_size,
                              hipStream_t stream) {
    const float* x     = (const float*)d_in[0];
    const float* cosb  = (const float*)d_in[1];
    const float* sinb  = (const float*)d_in[2];
    const float* maskb = (const float*)d_in[3];
    const float* Wq    = (const float*)d_in[4];
    const float* Wk    = (const float*)d_in[5];
    const float* Wv    = (const float*)d_in[6];
    const float* Wo    = (const float*)d_in[7];

    const int M = B_ * S_;   // 4096

    // ws: qkv | Wqkvt | Wot | Vtg  (19.9 MB bf16).
    // d_out doubles as scratch: xb = bf16(x) lives there until gemm2
    // overwrites it with the final fp32 output.
    short* qkv   = (short*)d_ws;                     // [4096][1536]
    short* Wqkvt = qkv + (size_t)M * QKVW;           // [1536][1024]
    short* Wot   = Wqkvt + (size_t)QKVW * H_;        // [1024][1024]
    short* Vtg   = Wot + (size_t)H_ * H_;            // [8*64][2048]
    short* xb    = (short*)d_out;                    // [4096][1024] bf16 scratch
    float* out   = (float*)d_out;

    dim3 blk(256);

    // transposes + x->bf16 convert
    tconv_all<<<dim3(896), blk, 0, stream>>>(Wq, Wk, Wv, Wo, Wqkvt, Wot, x, xb);

    // GEMM1 fused (64x128 tile, 768 blocks = 3 exact rounds, 3 blocks/CU)
    gemm1_fused<<<dim3(QKVW / 128, M / 64), blk, 0, stream>>>(xb, Wqkvt, qkv, Vtg, cosb, sinb);

    // attention: 256 pair-blocks x 512 threads, uniform 34 steps/block
    attn_kernel<<<dim3(256), dim3(512), 0, stream>>>(qkv, Vtg, maskb);

    // GEMM2 (64x128 tile, 512 blocks = 2 exact rounds): out = attn @ Wot^T
    gemm2_bt<<<dim3(H_ / 128, M / 64), blk, 0, stream>>>(qkv, QKVW, Wot, out, H_, H_);
}

// Round 9
// 183.665 us; speedup vs baseline: 1.1251x; 1.0039x over previous
//
#include <hip/hip_runtime.h>
#include <math.h>

#define B_   2
#define S_   2048
#define H_   1024
#define NH_  16
#define NKV_ 4
#define HD_  64
#define R_   (NH_ / NKV_)   // 4 q-heads per kv-head
#define QKVW 1536           // qkv row width (q 0..1023 | k 1024..1279 | v 1280..1535)

typedef __attribute__((ext_vector_type(8))) short bf16x8;
typedef __attribute__((ext_vector_type(4))) float f32x4;

__device__ inline short f2bf(float f) {
    unsigned u = __float_as_uint(f);
    u += 0x7FFF + ((u >> 16) & 1);     // RNE to bf16
    return (short)(u >> 16);
}

// native 2^x (v_exp_f32). Builtin if available (compiler handles trans-op
// hazards); asm fallback carries its own s_nop wait-state.
__device__ inline float exp2fast(float x) {
#if __has_builtin(__builtin_amdgcn_exp2f)
    return __builtin_amdgcn_exp2f(x);
#else
    float r; asm volatile("v_exp_f32 %0, %1\n\ts_nop 1" : "=v"(r) : "v"(x)); return r;
#endif
}

// pack 2 fp32 -> 2 bf16 (RNE) in one instr (T12 recipe; no builtin on gfx950)
__device__ inline unsigned cvt_pk_bf16(float lo, float hi) {
    unsigned r;
    asm("v_cvt_pk_bf16_f32 %0, %1, %2" : "=v"(r) : "v"(lo), "v"(hi));
    return r;
}

#define LOG2E 1.4426950408889634f

// async global->LDS, 16 B per lane; lptr is the wave-uniform chunk base,
// HW scatters lane i's 16 B at lptr + i*16 (m97/m104 semantics).
__device__ inline void gload_lds16(const void* gptr, void* lptr) {
    __builtin_amdgcn_global_load_lds(
        (const __attribute__((address_space(1))) unsigned int*)gptr,
        (__attribute__((address_space(3))) unsigned int*)lptr,
        16, 0, 0);
}

// ---------------------------------------------------------------------------
// Weight transposes + x->bf16 convert in one launch. 896 blocks:
// [0,640) = 64x64 transpose tiles (Wq/Wk/Wv/Wo); [640,896) = xb = bf16(x).
// ---------------------------------------------------------------------------
__global__ __launch_bounds__(256) void tconv_all(const float* __restrict__ Wq,
                                                 const float* __restrict__ Wk,
                                                 const float* __restrict__ Wv,
                                                 const float* __restrict__ Wo,
                                                 short* __restrict__ Wqkvt,
                                                 short* __restrict__ Wot,
                                                 const float* __restrict__ x,
                                                 short* __restrict__ xb) {
    const int bx = blockIdx.x;
    const int tid = threadIdx.x;

    if (bx >= 640) {           // ---- x -> bf16 convert ----
        const size_t e0 = (size_t)(bx - 640) * 16384;
#pragma unroll
        for (int t = 0; t < 8; t++) {
            const size_t i = e0 + ((size_t)t * 256 + tid) * 8;
            float4 a = *(const float4*)&x[i];
            float4 c = *(const float4*)&x[i + 4];
            bf16x8 o;
            o[0] = f2bf(a.x); o[1] = f2bf(a.y); o[2] = f2bf(a.z); o[3] = f2bf(a.w);
            o[4] = f2bf(c.x); o[5] = f2bf(c.y); o[6] = f2bf(c.z); o[7] = f2bf(c.w);
            *(bf16x8*)&xb[i] = o;
        }
        return;
    }

    __shared__ short T[64][68];
    const float* W; short* Wt; int N, idx;
    if (bx < 256)      { W = Wq; Wt = Wqkvt;                     N = 1024; idx = bx; }
    else if (bx < 320) { W = Wk; Wt = Wqkvt + 1024 * 1024;       N = 256;  idx = bx - 256; }
    else if (bx < 384) { W = Wv; Wt = Wqkvt + 1280 * 1024;       N = 256;  idx = bx - 320; }
    else               { W = Wo; Wt = Wot;                       N = 1024; idx = bx - 384; }
    const int ntiles = N >> 6;
    const int n0 = (idx % ntiles) * 64;
    const int k0 = (idx / ntiles) * 64;

    const int r  = tid >> 4;
    const int c4 = (tid & 15) * 4;
#pragma unroll
    for (int t = 0; t < 4; t++) {
        int row = t * 16 + r;
        float4 v = *(const float4*)&W[(size_t)(k0 + row) * N + n0 + c4];
        T[c4 + 0][row] = f2bf(v.x);
        T[c4 + 1][row] = f2bf(v.y);
        T[c4 + 2][row] = f2bf(v.z);
        T[c4 + 3][row] = f2bf(v.w);
    }
    __syncthreads();
#pragma unroll
    for (int t = 0; t < 4; t++) {
        int row = t * 16 + r;          // n index
        short4 o = *(short4*)&T[row][c4];
        *(short4*)&Wt[(size_t)(n0 + row) * 1024 + k0 + c4] = o;
    }
}

// ---------------------------------------------------------------------------
// Fused GEMM1 v4: qkv = xb @ Wqkvt^T, 64x128 tile, BK=32, 2-PHASE
// double-buffered LDS (T3 minimum pattern): issue next tile's glds into
// buf^1 BEFORE compute of buf, ONE barrier/iter — its vmcnt(0) drain lands
// after ~250cy of ds_read+MFMA instead of overlapping nothing (the R8
// structure drained the glds immediately: 2 barriers/iter, latency fully
// exposed). LDS 24 KB -> ~3 co-resident blocks/CU (768-block grid = 3/CU,
// all resident). RoPE epilogue q/k; v transposed-scatter into Vtg.
// ---------------------------------------------------------------------------
__global__ __launch_bounds__(256) void gemm1_fused(const short* __restrict__ xb,
                                                   const short* __restrict__ Bt,
                                                   short* __restrict__ qkv,
                                                   short* __restrict__ Vtg,
                                                   const float* __restrict__ cosb,
                                                   const float* __restrict__ sinb) {
    __shared__ short Ah[2][64 * 32];    // 2 x 4 KB
    __shared__ short Bh[2][128 * 32];   // 2 x 8 KB

    const int tid  = threadIdx.x;
    const int w    = tid >> 6;
    const int lane = tid & 63;
    const int ln   = lane & 15;
    const int qd   = lane >> 4;
    const int wr   = w >> 1, wc = w & 1;
    const int row0 = blockIdx.y * 64;
    const int col0 = blockIdx.x * 128;

    const int sr = lane >> 2;        // 0..15 staging row-in-chunk
    const int sk = (lane & 3) * 8;   // k element offset

    const short* ap = xb + (size_t)(row0 + w * 16 + sr) * 1024 + sk;
    const short* bp0 = Bt + (size_t)(col0 + w * 32 + sr) * 1024 + sk;
    const short* bp1 = Bt + (size_t)(col0 + w * 32 + 16 + sr) * 1024 + sk;

    f32x4 acc[2][4];
#pragma unroll
    for (int mi = 0; mi < 2; mi++)
#pragma unroll
        for (int ni = 0; ni < 4; ni++)
            acc[mi][ni] = (f32x4){0.f, 0.f, 0.f, 0.f};

    // prologue: stage tile 0 into buf 0
    gload_lds16(ap,  &Ah[0][(w * 16) * 32]);
    gload_lds16(bp0, &Bh[0][(w * 32) * 32]);
    gload_lds16(bp1, &Bh[0][(w * 32 + 16) * 32]);
    __syncthreads();

    for (int t = 0; t < 32; t++) {
        const int cur = t & 1, nxt = cur ^ 1;
        if (t + 1 < 32) {   // issue next tile's staging FIRST (overlaps MFMA)
            const int k1 = (t + 1) * 32;
            gload_lds16(ap + k1,  &Ah[nxt][(w * 16) * 32]);
            gload_lds16(bp0 + k1, &Bh[nxt][(w * 32) * 32]);
            gload_lds16(bp1 + k1, &Bh[nxt][(w * 32 + 16) * 32]);
        }

        bf16x8 af[2], bfr[4];
#pragma unroll
        for (int mi = 0; mi < 2; mi++)
            af[mi] = *(const bf16x8*)&Ah[cur][(wr * 32 + mi * 16 + ln) * 32 + qd * 8];
#pragma unroll
        for (int ni = 0; ni < 4; ni++)
            bfr[ni] = *(const bf16x8*)&Bh[cur][(wc * 64 + ni * 16 + ln) * 32 + qd * 8];
#pragma unroll
        for (int mi = 0; mi < 2; mi++)
#pragma unroll
            for (int ni = 0; ni < 4; ni++)
                acc[mi][ni] = __builtin_amdgcn_mfma_f32_16x16x32_bf16(af[mi], bfr[ni], acc[mi][ni], 0, 0, 0);

        __syncthreads();   // vmcnt(0) drain here lands AFTER the MFMAs
    }

    const int colw = col0 + wc * 64;          // this wave's 64-col half
    if (colw < H_ + NKV_ * HD_) {
        // ---- q or k columns: RoPE in fp32, store bf16 to qkv ----
#pragma unroll
        for (int mi = 0; mi < 2; mi++)
#pragma unroll
            for (int i = 0; i < 4; i++) {
                const int row  = row0 + wr * 32 + mi * 16 + qd * 4 + i;
                const int spos = row & (S_ - 1);
                const float* cp = cosb + (size_t)spos * HD_;
                const float* sp = sinb + (size_t)spos * HD_;
                float o0[4];
#pragma unroll
                for (int ni = 0; ni < 2; ni++) {
                    const int d = ni * 16 + ln;
                    float x0 = acc[mi][ni][i], x1 = acc[mi][ni + 2][i];
                    o0[ni]     = x0 * cp[d]      - x1 * sp[d];
                    o0[ni + 2] = x1 * cp[d + 32] + x0 * sp[d + 32];
                }
                short* Cp = qkv + (size_t)row * QKVW + colw + ln;
#pragma unroll
                for (int ni = 0; ni < 4; ni++) Cp[ni * 16] = f2bf(o0[ni]);
            }
    } else {
        // ---- v columns: transposed scatter into Vtg[(b*NKV+g)*HD+d][s] ----
        const int g = (colw - (H_ + NKV_ * HD_)) >> 6;
#pragma unroll
        for (int mi = 0; mi < 2; mi++) {
            const int rbase = row0 + wr * 32 + mi * 16 + qd * 4;   // i = +0..3
            const int bg = ((rbase >> 11) * NKV_) + g;
            const int s0 = rbase & (S_ - 1);
#pragma unroll
            for (int ni = 0; ni < 4; ni++) {
                const int d = ni * 16 + ln;
                short4 pk = { f2bf(acc[mi][ni][0]), f2bf(acc[mi][ni][1]),
                              f2bf(acc[mi][ni][2]), f2bf(acc[mi][ni][3]) };
                *(short4*)&Vtg[((size_t)bg * HD_ + d) * S_ + s0] = pk;
            }
        }
    }
}

// ---------------------------------------------------------------------------
// bf16 MFMA GEMM v3, B^T form: C[M,N] = A[M,K] @ Bt[N,K]^T (fp32 out).
// 64x128 tile, BK=32, 2-phase double-buffered LDS (same pattern as gemm1).
// ---------------------------------------------------------------------------
__global__ __launch_bounds__(256) void gemm2_bt(const short* __restrict__ A, int lda,
                                                const short* __restrict__ Bt,
                                                float* __restrict__ C, int ldc,
                                                int K) {
    __shared__ short Ah[2][64 * 32];
    __shared__ short Bh[2][128 * 32];

    const int tid  = threadIdx.x;
    const int w    = tid >> 6;
    const int lane = tid & 63;
    const int ln   = lane & 15;
    const int qd   = lane >> 4;
    const int wr   = w >> 1, wc = w & 1;
    const int row0 = blockIdx.y * 64;
    const int col0 = blockIdx.x * 128;

    const int sr = lane >> 2;
    const int sk = (lane & 3) * 8;

    const short* ap  = A + (size_t)(row0 + w * 16 + sr) * lda + sk;
    const short* bp0 = Bt + (size_t)(col0 + w * 32 + sr) * K + sk;
    const short* bp1 = Bt + (size_t)(col0 + w * 32 + 16 + sr) * K + sk;

    f32x4 acc[2][4];
#pragma unroll
    for (int mi = 0; mi < 2; mi++)
#pragma unroll
        for (int ni = 0; ni < 4; ni++)
            acc[mi][ni] = (f32x4){0.f, 0.f, 0.f, 0.f};

    const int nt = K >> 5;
    gload_lds16(ap,  &Ah[0][(w * 16) * 32]);
    gload_lds16(bp0, &Bh[0][(w * 32) * 32]);
    gload_lds16(bp1, &Bh[0][(w * 32 + 16) * 32]);
    __syncthreads();

    for (int t = 0; t < nt; t++) {
        const int cur = t & 1, nxt = cur ^ 1;
        if (t + 1 < nt) {
            const int k1 = (t + 1) * 32;
            gload_lds16(ap + k1,  &Ah[nxt][(w * 16) * 32]);
            gload_lds16(bp0 + k1, &Bh[nxt][(w * 32) * 32]);
            gload_lds16(bp1 + k1, &Bh[nxt][(w * 32 + 16) * 32]);
        }

        bf16x8 af[2], bfr[4];
#pragma unroll
        for (int mi = 0; mi < 2; mi++)
            af[mi] = *(const bf16x8*)&Ah[cur][(wr * 32 + mi * 16 + ln) * 32 + qd * 8];
#pragma unroll
        for (int ni = 0; ni < 4; ni++)
            bfr[ni] = *(const bf16x8*)&Bh[cur][(wc * 64 + ni * 16 + ln) * 32 + qd * 8];
#pragma unroll
        for (int mi = 0; mi < 2; mi++)
#pragma unroll
            for (int ni = 0; ni < 4; ni++)
                acc[mi][ni] = __builtin_amdgcn_mfma_f32_16x16x32_bf16(af[mi], bfr[ni], acc[mi][ni], 0, 0, 0);

        __syncthreads();
    }

#pragma unroll
    for (int mi = 0; mi < 2; mi++)
#pragma unroll
        for (int i = 0; i < 4; i++) {
            const size_t row = row0 + wr * 32 + mi * 16 + qd * 4 + i;
            float* Cp = C + row * ldc + col0 + wc * 64 + ln;
#pragma unroll
            for (int ni = 0; ni < 4; ni++) Cp[ni * 16] = acc[mi][ni][i];
        }
}

// ---------------------------------------------------------------------------
// bf16 MFMA flash attention v17 (UNCHANGED from R8, measured 60.5 us):
// uniform 34-step pair-blocks + log2-domain softmax + cvt_pk P-pack.
// R8 post-mortem: VALUBusy 25.9 (diet worked) but time -1.7us only ->
// dependency-latency-bound at 2 waves/SIMD; left alone.
// ---------------------------------------------------------------------------
__global__ __launch_bounds__(512, 2) void attn_kernel(short* __restrict__ qkv,
                                                      const short* __restrict__ Vtg,
                                                      const float* __restrict__ maskb) {
    const int tid  = threadIdx.x;
    const int w    = tid >> 6;           // 0..7
    const int lane = tid & 63;
    const int ln   = lane & 15;
    const int qd   = lane >> 4;

    // fid&7 = bg -> XCD affinity for the K/V slice
    const int fid = blockIdx.x;          // 0..255
    const int bg  = fid & 7;             // b*NKV+g
    const int u   = fid >> 3;            // 0..31
    const int b   = bg >> 2;
    const int g   = bg & 3;
    const int h   = g * R_ + (u & 3);
    const int a   = u >> 2;              // pair index 0..7

    __shared__ short Ks[2][64 * 72];     // K  [key][dim], stride 72
    __shared__ short Vt[2][64 * 72];     // V^T [dim][key]
    __shared__ short Ps[8][16 * 72];     // per-wave P round-trip
    __shared__ float mskS[2][64];        // PRE-BIASED+SCALED: (1-m)*-1e9*log2e
    short* const ps = Ps[w];

    const short* const Kb = qkv + (size_t)b * S_ * QKVW + H_ + g * HD_;
    const short* const Vb = Vtg + (size_t)bg * HD_ * S_;
    const float* const mb = maskb + b * S_;

    const int fr = tid >> 3;             // 0..63 (staging row)
    const int fc = (tid & 7) * 8;        // staging col (elements)

#pragma unroll 1
    for (int ph = 0; ph < 2; ph++) {
        const int qt   = ph ? (15 - a) : a;
        const int rowb = qt * 128 + w * 16;   // this wave's 16-row strip
        const int ktd  = 2 * qt + (w >> 2);   // wave's diagonal tile
        const int ntp  = 2 * qt + 2;          // tiles this phase
        const int qrow = rowb + ln;

        // ---- Q B-frags: rows rowb+ln ----
        bf16x8 qf0, qf1;
        {
            const short* qp = qkv + (size_t)(b * S_ + rowb + ln) * QKVW + h * HD_;
            qf0 = *(const bf16x8*)&qp[qd * 8];
            qf1 = *(const bf16x8*)&qp[32 + qd * 8];
        }

        f32x4 O[4] = {};
        float mrow = -1e30f, lrow = 0.0f;    // mrow in log2 units

        // ---- stage tile 0 ----
        *(bf16x8*)&Ks[0][fr * 72 + fc] = *(const bf16x8*)&Kb[(size_t)fr * QKVW + fc];
        *(bf16x8*)&Vt[0][fr * 72 + fc] = *(const bf16x8*)&Vb[(size_t)fr * S_ + fc];
        if (tid < 64) mskS[0][tid] = (1.0f - mb[tid]) * (-1e9f * LOG2E);
        __syncthreads();

        int cur = 0;
#pragma unroll 1
        for (int kt = 0; kt < ntp; kt++) {
            const int base = kt * 64;
            const bool pf = (kt + 1 < ntp);

            // ---- prefetch tile kt+1 into registers (no wait) ----
            bf16x8 pk, pv;
            float pm = 0.0f;
            if (pf) {
                const int nb = base + 64;
                pk = *(const bf16x8*)&Kb[(size_t)(nb + fr) * QKVW + fc];
                pv = *(const bf16x8*)&Vb[(size_t)fr * S_ + nb + fc];
                if (tid < 64) pm = (1.0f - mb[nb + tid]) * (-1e9f * LOG2E);
            }

            if (kt <= ktd) {   // wave-uniform
                // ---- QK^T swapped: St[kg] = S^T[key][qrow=ln] ----
                f32x4 St[4];
#pragma unroll
                for (int kg = 0; kg < 4; kg++) {
                    bf16x8 ka0 = *(const bf16x8*)&Ks[cur][(kg * 16 + ln) * 72 + qd * 8];
                    bf16x8 ka1 = *(const bf16x8*)&Ks[cur][(kg * 16 + ln) * 72 + 32 + qd * 8];
                    f32x4 z = {0.f, 0.f, 0.f, 0.f};
                    z = __builtin_amdgcn_mfma_f32_16x16x32_bf16(ka0, qf0, z, 0, 0, 0);
                    St[kg] = __builtin_amdgcn_mfma_f32_16x16x32_bf16(ka1, qf1, z, 0, 0, 0);
                }

                // ---- V B-frags from LDS ----
                bf16x8 vb[2][4];
#pragma unroll
                for (int kc2 = 0; kc2 < 2; kc2++)
#pragma unroll
                    for (int dt = 0; dt < 4; dt++)
                        vb[kc2][dt] = *(const bf16x8*)&Vt[cur][(dt * 16 + ln) * 72 + kc2 * 32 + qd * 8];

                // ---- log2-domain scale + pre-scaled mask; causal on diag ----
                float sc[4][4];
#pragma unroll
                for (int kg = 0; kg < 4; kg++) {
                    float4 mv = *(const float4*)&mskS[cur][kg * 16 + qd * 4];
                    sc[kg][0] = fmaf(St[kg][0], 0.125f * LOG2E, mv.x);
                    sc[kg][1] = fmaf(St[kg][1], 0.125f * LOG2E, mv.y);
                    sc[kg][2] = fmaf(St[kg][2], 0.125f * LOG2E, mv.z);
                    sc[kg][3] = fmaf(St[kg][3], 0.125f * LOG2E, mv.w);
                }
                if (kt == ktd) {
#pragma unroll
                    for (int kg = 0; kg < 4; kg++) {
                        const int keyb = base + kg * 16 + qd * 4;
#pragma unroll
                        for (int i = 0; i < 4; i++)
                            if (keyb + i > qrow) sc[kg][i] = -1e30f;
                    }
                }

                float mx = sc[0][0];
#pragma unroll
                for (int kg = 0; kg < 4; kg++)
#pragma unroll
                    for (int i = 0; i < 4; i++) mx = fmaxf(mx, sc[kg][i]);
                mx = fmaxf(mx, __shfl_xor(mx, 16));
                mx = fmaxf(mx, __shfl_xor(mx, 32));

                // defer-max (T13): 8 ln-units = 11.5416 log2-units
                if (__ballot(mx > mrow + 11.5416f)) {
                    float nm    = fmaxf(mrow, mx);
                    float alpha = exp2fast(mrow - nm);
                    lrow *= alpha;
#pragma unroll
                    for (int i = 0; i < 4; i++) {
                        float av = __shfl(alpha, qd * 4 + i);
#pragma unroll
                        for (int dt = 0; dt < 4; dt++) O[dt][i] *= av;
                    }
                    mrow = nm;
                }
                const float nm = mrow;

                float ls = 0.0f;
#pragma unroll
                for (int kg = 0; kg < 4; kg++)
#pragma unroll
                    for (int i = 0; i < 4; i++) {
                        float p = exp2fast(sc[kg][i] - nm);
                        sc[kg][i] = p;
                        ls += p;
                    }
                ls += __shfl_xor(ls, 16);
                ls += __shfl_xor(ls, 32);
                lrow += ls;

                // ---- P pack via cvt_pk (2 f32 -> 1 u32 of 2 bf16) ----
#pragma unroll
                for (int kg = 0; kg < 4; kg++) {
                    uint2 pw;
                    pw.x = cvt_pk_bf16(sc[kg][0], sc[kg][1]);
                    pw.y = cvt_pk_bf16(sc[kg][2], sc[kg][3]);
                    *(uint2*)&ps[ln * 72 + kg * 16 + qd * 4] = pw;
                }

                // ---- PV: O += P @ V (same-wave LDS write->read) ----
#pragma unroll
                for (int kc2 = 0; kc2 < 2; kc2++) {
                    bf16x8 pa = *(const bf16x8*)&ps[ln * 72 + kc2 * 32 + qd * 8];
#pragma unroll
                    for (int dt = 0; dt < 4; dt++)
                        O[dt] = __builtin_amdgcn_mfma_f32_16x16x32_bf16(pa, vb[kc2][dt], O[dt], 0, 0, 0);
                }
            }

            // ---- write prefetched tile into the other buffer ----
            if (pf) {
                const int nxt = cur ^ 1;
                *(bf16x8*)&Ks[nxt][fr * 72 + fc] = pk;
                *(bf16x8*)&Vt[nxt][fr * 72 + fc] = pv;
                if (tid < 64) mskS[nxt][tid] = pm;
            }
            __syncthreads();
            cur ^= 1;
        }

        // ---- finalize this phase: write bf16 into q-slice ----
#pragma unroll
        for (int i = 0; i < 4; i++) {
            float li  = __shfl(lrow, qd * 4 + i);
            float inv = 1.0f / li;
            const int row = rowb + qd * 4 + i;
            short* op = qkv + (size_t)(b * S_ + row) * QKVW + h * HD_ + ln;
#pragma unroll
            for (int dt = 0; dt < 4; dt++) op[dt * 16] = f2bf(O[dt][i] * inv);
        }
    }
}

// ---------------------------------------------------------------------------
extern "C" void kernel_launch(void* const* d_in, const int* in_sizes, int n_in,
                              void* d_out, int out_size, void* d_ws, size_t ws_size,
                              hipStream_t stream) {
    const float* x     = (const float*)d_in[0];
    const float* cosb  = (const float*)d_in[1];
    const float* sinb  = (const float*)d_in[2];
    const float* maskb = (const float*)d_in[3];
    const float* Wq    = (const float*)d_in[4];
    const float* Wk    = (const float*)d_in[5];
    const float* Wv    = (const float*)d_in[6];
    const float* Wo    = (const float*)d_in[7];

    const int M = B_ * S_;   // 4096

    // ws: qkv | Wqkvt | Wot | Vtg  (19.9 MB bf16).
    // d_out doubles as scratch: xb = bf16(x) lives there until gemm2
    // overwrites it with the final fp32 output.
    short* qkv   = (short*)d_ws;                     // [4096][1536]
    short* Wqkvt = qkv + (size_t)M * QKVW;           // [1536][1024]
    short* Wot   = Wqkvt + (size_t)QKVW * H_;        // [1024][1024]
    short* Vtg   = Wot + (size_t)H_ * H_;            // [8*64][2048]
    short* xb    = (short*)d_out;                    // [4096][1024] bf16 scratch
    float* out   = (float*)d_out;

    dim3 blk(256);

    // transposes + x->bf16 convert
    tconv_all<<<dim3(896), blk, 0, stream>>>(Wq, Wk, Wv, Wo, Wqkvt, Wot, x, xb);

    // GEMM1 fused (64x128 tile, 2-phase dbuf, 768 blocks all co-resident)
    gemm1_fused<<<dim3(QKVW / 128, M / 64), blk, 0, stream>>>(xb, Wqkvt, qkv, Vtg, cosb, sinb);

    // attention: 256 pair-blocks x 512 threads, uniform 34 steps/block
    attn_kernel<<<dim3(256), dim3(512), 0, stream>>>(qkv, Vtg, maskb);

    // GEMM2 (64x128 tile, 2-phase dbuf): out = attn @ Wot^T
    gemm2_bt<<<dim3(H_ / 128, M / 64), blk, 0, stream>>>(qkv, QKVW, Wot, out, H_, H_);
}